// Round 1
// baseline (4536.268 us; speedup 1.0000x reference)
//
#include <hip/hip_runtime.h>
#include <cstdint>
#include <cstddef>

// ---------------------------------------------------------------------------
// Generic fp32 tiled GEMM: C[M,N] = epilogue(A[M,K] @ B[K,N])
// epilogue: v = acc; if(addm) v += addm[r,c]; if(rowscale) v *= rs[r];
//           if(bias) v += bias[c]; if(relu) v = max(v,0)
// Requirements: M % 128 == 0, N % 128 == 0 (K arbitrary, guarded).
// ---------------------------------------------------------------------------
#define GBM 128
#define GBN 128
#define GBK 16
#define GLT 132   // padded leading dim for LDS tiles (16B-aligned rows, 2-way banks)

__global__ __launch_bounds__(256) void gemm128(
    const float* __restrict__ A, long lda, long sAb,
    const float* __restrict__ B, long ldb, long sBb,
    float* __restrict__ C, long ldc, long sCb,
    int M, int N, int K,
    const float* __restrict__ bias,
    const float* __restrict__ rowscale,
    const float* __restrict__ addm, long sAddb, long ldadd,
    int do_relu)
{
  __shared__ __align__(16) float Ast[GBK * GLT];  // transposed: Ast[k][r]
  __shared__ __align__(16) float Bs[GBK * GLT];   // Bs[k][c]
  const int bz = blockIdx.z;
  const float* Ab = A + (size_t)bz * sAb;
  const float* Bb = B + (size_t)bz * sBb;
  float* Cb = C + (size_t)bz * sCb;
  const int row0 = blockIdx.y * GBM;
  const int col0 = blockIdx.x * GBN;
  const int t = threadIdx.x;
  const int tx = t & 15, ty = t >> 4;

  float acc[8][8];
#pragma unroll
  for (int i = 0; i < 8; ++i)
#pragma unroll
    for (int j = 0; j < 8; ++j) acc[i][j] = 0.f;

  for (int k0 = 0; k0 < K; k0 += GBK) {
    __syncthreads();
#pragma unroll
    for (int it = 0; it < 8; ++it) {
      int lin = t + 256 * it;
      int r = lin >> 4, kc = lin & 15;
      int kg = k0 + kc;
      Ast[kc * GLT + r] = (kg < K) ? Ab[(size_t)(row0 + r) * lda + kg] : 0.f;
    }
#pragma unroll
    for (int it = 0; it < 8; ++it) {
      int lin = t + 256 * it;
      int kr = lin >> 7, c = lin & 127;
      int kg = k0 + kr;
      Bs[kr * GLT + c] = (kg < K) ? Bb[(size_t)kg * ldb + col0 + c] : 0.f;
    }
    __syncthreads();
#pragma unroll
    for (int kk = 0; kk < GBK; ++kk) {
      const float4 a0 = *(const float4*)&Ast[kk * GLT + ty * 4];
      const float4 a1 = *(const float4*)&Ast[kk * GLT + 64 + ty * 4];
      const float4 b0 = *(const float4*)&Bs[kk * GLT + tx * 4];
      const float4 b1 = *(const float4*)&Bs[kk * GLT + 64 + tx * 4];
      const float av[8] = {a0.x, a0.y, a0.z, a0.w, a1.x, a1.y, a1.z, a1.w};
      const float bv[8] = {b0.x, b0.y, b0.z, b0.w, b1.x, b1.y, b1.z, b1.w};
#pragma unroll
      for (int i = 0; i < 8; ++i)
#pragma unroll
        for (int j = 0; j < 8; ++j) acc[i][j] = fmaf(av[i], bv[j], acc[i][j]);
    }
  }

#pragma unroll
  for (int i = 0; i < 8; ++i) {
    const int r = row0 + ((i < 4) ? ty * 4 + i : 64 + ty * 4 + (i - 4));
    const float rs = rowscale ? rowscale[(size_t)bz * M + r] : 1.f;
#pragma unroll
    for (int j = 0; j < 8; ++j) {
      const int c = col0 + ((j < 4) ? tx * 4 + j : 64 + tx * 4 + (j - 4));
      float v = acc[i][j];
      if (addm) v += addm[(size_t)bz * sAddb + (size_t)r * ldadd + c];
      v *= rs;
      if (bias) v += bias[c];
      if (do_relu) v = fmaxf(v, 0.f);
      Cb[(size_t)r * ldc + c] = v;
    }
  }
}

// ---------------------------------------------------------------------------
// lin2: h[:, :, 0:21] = relu(x[:, :, 0:21] @ W2[21,21] + b2)
// ---------------------------------------------------------------------------
__global__ void lin2_kernel(const float* __restrict__ x, const float* __restrict__ W,
                            const float* __restrict__ b, float* __restrict__ h)
{
  int id = blockIdx.x * blockDim.x + threadIdx.x;
  if (id >= 4 * 2048 * 21) return;
  int row = id / 21, j = id % 21;
  const float* xr = x + (size_t)row * 6165;
  float acc = b[j];
  for (int i = 0; i < 21; ++i) acc = fmaf(xr[i], W[i * 21 + j], acc);
  h[(size_t)row * 544 + j] = fmaxf(acc, 0.f);
}

// ---------------------------------------------------------------------------
// degrees of original adj: dg = rsqrt(rowsum+1) [GCN w/ self-loop], dp = 1/max(rowsum,1) [pool]
// ---------------------------------------------------------------------------
__global__ __launch_bounds__(256) void degrees_kernel(const float* __restrict__ adj,
                                                      float* __restrict__ dg,
                                                      float* __restrict__ dp)
{
  __shared__ float red[256];
  const int row = blockIdx.x;
  const int t = threadIdx.x;
  const float* ar = adj + (size_t)row * 2048;
  float s = 0.f;
  for (int j = t; j < 2048; j += 256) s += ar[j];
  red[t] = s; __syncthreads();
  for (int off = 128; off > 0; off >>= 1) {
    if (t < off) red[t] += red[t + off];
    __syncthreads();
  }
  if (t == 0) {
    float S = red[0];
    dg[row] = rsqrtf(fmaxf(S + 1.f, 1e-12f));
    dp[row] = 1.f / fmaxf(S, 1.f);
  }
}

// ---------------------------------------------------------------------------
// conv1 message passing (sparse): out = relu(di * sum_{j in N(i)+self} a_ij*dj*xw_j + bias)
// Deterministic neighbor list: per-thread segment scan + prefix sum (no atomics).
// ---------------------------------------------------------------------------
__global__ __launch_bounds__(256) void conv1_msg_kernel(
    const float* __restrict__ adj, const float* __restrict__ xw,
    const float* __restrict__ dinv, const float* __restrict__ bias,
    float* __restrict__ out)
{
  __shared__ int nbr[2048];
  __shared__ float nval[2048];
  __shared__ int cnts[256];
  const int b = blockIdx.y, i = blockIdx.x, t = threadIdx.x;
  const float* ar = adj + ((size_t)(b * 2048 + i)) * 2048;
  int myj[8]; float myv[8]; int mc = 0;
  const int j0 = t * 8;
#pragma unroll
  for (int q = 0; q < 8; ++q) {
    float v = ar[j0 + q];
    if (v != 0.f) { myj[mc] = j0 + q; myv[mc] = v; ++mc; }
  }
  cnts[t] = mc; __syncthreads();
  for (int off = 1; off < 256; off <<= 1) {
    int v = cnts[t]; int add = (t >= off) ? cnts[t - off] : 0;
    __syncthreads();
    cnts[t] = v + add; __syncthreads();
  }
  const int base = cnts[t] - mc;
  const int total = cnts[255];
  for (int q = 0; q < mc; ++q) { nbr[base + q] = myj[q]; nval[base + q] = myv[q]; }
  __syncthreads();

  const float* xwb = xw + (size_t)b * 2048 * 512;
  const float* dv = dinv + b * 2048;
  float acc0 = 0.f, acc1 = 0.f;
  for (int n = 0; n < total; ++n) {
    const int j = nbr[n];
    const float w = nval[n] * dv[j];
    const float* xr = xwb + (size_t)j * 512;
    acc0 = fmaf(w, xr[t], acc0);
    acc1 = fmaf(w, xr[t + 256], acc1);
  }
  const float di = dv[i];
  const float* xi = xwb + (size_t)i * 512;
  acc0 = fmaf(di, xi[t], acc0);
  acc1 = fmaf(di, xi[t + 256], acc1);
  float* orow = out + ((size_t)(b * 2048 + i)) * 512;
  orow[t]       = fmaxf(di * acc0 + bias[t], 0.f);
  orow[t + 256] = fmaxf(di * acc1 + bias[t + 256], 0.f);
}

// ---------------------------------------------------------------------------
// pool1 score (sparse): score_i = sum_c | h_ic - dp_i * sum_j a_ij h_jc |
// ---------------------------------------------------------------------------
__global__ __launch_bounds__(256) void pool1_score_kernel(
    const float* __restrict__ adj, const float* __restrict__ h1,
    const float* __restrict__ dpool, float* __restrict__ score)
{
  __shared__ int nbr[2048];
  __shared__ float nval[2048];
  __shared__ int cnts[256];
  __shared__ float red[256];
  const int b = blockIdx.y, i = blockIdx.x, t = threadIdx.x;
  const float* ar = adj + ((size_t)(b * 2048 + i)) * 2048;
  int myj[8]; float myv[8]; int mc = 0;
  const int j0 = t * 8;
#pragma unroll
  for (int q = 0; q < 8; ++q) {
    float v = ar[j0 + q];
    if (v != 0.f) { myj[mc] = j0 + q; myv[mc] = v; ++mc; }
  }
  cnts[t] = mc; __syncthreads();
  for (int off = 1; off < 256; off <<= 1) {
    int v = cnts[t]; int add = (t >= off) ? cnts[t - off] : 0;
    __syncthreads();
    cnts[t] = v + add; __syncthreads();
  }
  const int base = cnts[t] - mc;
  const int total = cnts[255];
  for (int q = 0; q < mc; ++q) { nbr[base + q] = myj[q]; nval[base + q] = myv[q]; }
  __syncthreads();

  const float* hb = h1 + (size_t)b * 2048 * 512;
  float acc0 = 0.f, acc1 = 0.f;
  for (int n = 0; n < total; ++n) {
    const int j = nbr[n];
    const float w = nval[n];
    const float* xr = hb + (size_t)j * 512;
    acc0 = fmaf(w, xr[t], acc0);
    acc1 = fmaf(w, xr[t + 256], acc1);
  }
  const float dpi = dpool[b * 2048 + i];
  const float* hi = hb + (size_t)i * 512;
  float part = fabsf(hi[t] - dpi * acc0) + fabsf(hi[t + 256] - dpi * acc1);
  red[t] = part; __syncthreads();
  for (int off = 128; off > 0; off >>= 1) {
    if (t < off) red[t] += red[t + off];
    __syncthreads();
  }
  if (t == 0) score[b * 2048 + i] = red[0];
}

// ---------------------------------------------------------------------------
// top-k: full bitonic sort of (score,~idx) packed u64 keys (descending), take
// first k indices, bitonic-sort them ascending. blockDim must be n/2 (== k).
// ---------------------------------------------------------------------------
__global__ __launch_bounds__(1024) void topk_kernel(
    const float* __restrict__ score, int* __restrict__ idx_out, int n, int k)
{
  __shared__ unsigned long long key[2048];
  const unsigned b = blockIdx.x, t = threadIdx.x;
  const unsigned bd = blockDim.x;  // n/2
  for (unsigned i = t; i < (unsigned)n; i += bd) {
    unsigned u = __float_as_uint(score[(size_t)b * n + i]);  // scores >= 0 -> monotone
    key[i] = ((unsigned long long)u << 32) | (unsigned)(~i);
  }
  __syncthreads();
  for (unsigned size = 2; size <= (unsigned)n; size <<= 1) {
    for (unsigned stride = size >> 1; stride > 0; stride >>= 1) {
      const unsigned i = (t / stride) * (stride * 2) + (t % stride);
      const unsigned ixj = i + stride;
      const bool up = ((i & size) == 0);
      unsigned long long a = key[i], c = key[ixj];
      if (up ? (a < c) : (a > c)) { key[i] = c; key[ixj] = a; }
      __syncthreads();
    }
  }
  // t < bd == k: extract selected indices
  const unsigned my = ~(unsigned)(key[t] & 0xFFFFFFFFull);
  __syncthreads();
  unsigned* arr = (unsigned*)key;
  arr[t] = my;
  __syncthreads();
  for (unsigned size = 2; size <= (unsigned)k; size <<= 1) {
    for (unsigned stride = size >> 1; stride > 0; stride >>= 1) {
      if (t < (unsigned)k / 2) {
        const unsigned i = (t / stride) * (stride * 2) + (t % stride);
        const unsigned ixj = i + stride;
        const bool up = ((i & size) == 0);
        unsigned a = arr[i], c = arr[ixj];
        if (up ? (a > c) : (a < c)) { arr[i] = c; arr[ixj] = a; }
      }
      __syncthreads();
    }
  }
  idx_out[(size_t)b * k + t] = (int)arr[t];
}

// ---------------------------------------------------------------------------
// gather pooled rows + li/lj attention dots
// ---------------------------------------------------------------------------
__global__ __launch_bounds__(256) void gather_li_kernel(
    const float* __restrict__ X, int src_n,
    const int* __restrict__ idx, int k,
    const float* __restrict__ att,
    float* __restrict__ xk, float* __restrict__ li, float* __restrict__ lj)
{
  __shared__ float redA[256], redB[256];
  const int b = blockIdx.y, r = blockIdx.x, t = threadIdx.x;
  const int g = idx[(size_t)b * k + r];
  const float* src = X + ((size_t)(b * src_n + g)) * 512;
  float* dst = xk + ((size_t)(b * k + r)) * 512;
  const float v0 = src[t], v1 = src[t + 256];
  dst[t] = v0; dst[t + 256] = v1;
  redA[t] = v0 * att[t] + v1 * att[t + 256];
  redB[t] = v0 * att[512 + t] + v1 * att[512 + t + 256];
  __syncthreads();
  for (int off = 128; off > 0; off >>= 1) {
    if (t < off) { redA[t] += redA[t + off]; redB[t] += redB[t + off]; }
    __syncthreads();
  }
  if (t == 0) { li[(size_t)b * k + r] = redA[0]; lj[(size_t)b * k + r] = redB[0]; }
}

// ---------------------------------------------------------------------------
// structure learning: adj_out[r,:] = softmax(li_r + lj_j + Asrc[gi,gj]); also
// emits GCN dinv (rsqrt(rowsum+1)) and pool dinv (1/max(rowsum,1)) of adj_out.
// ---------------------------------------------------------------------------
__global__ __launch_bounds__(256) void slearn_kernel(
    const float* __restrict__ Asrc, int src_n,
    const int* __restrict__ idx, int k,
    const float* __restrict__ li, const float* __restrict__ lj,
    float* __restrict__ adj_out, float* __restrict__ dg, float* __restrict__ dp)
{
  __shared__ int gidx[1024];
  __shared__ float ljv[1024];
  __shared__ float lg[1024];
  __shared__ float red[256];
  const int b = blockIdx.y, r = blockIdx.x, t = threadIdx.x;
  for (int j = t; j < k; j += 256) { gidx[j] = idx[(size_t)b * k + j]; ljv[j] = lj[(size_t)b * k + j]; }
  __syncthreads();
  const int gi = gidx[r];
  const float lir = li[(size_t)b * k + r];
  const float* ar = Asrc + ((size_t)(b * src_n + gi)) * src_n;
  float mx = -3.4e38f;
  for (int j = t; j < k; j += 256) {
    float v = lir + ljv[j] + ar[gidx[j]];   // LAMB = 1.0
    lg[j] = v; mx = fmaxf(mx, v);
  }
  red[t] = mx; __syncthreads();
  for (int off = 128; off > 0; off >>= 1) {
    if (t < off) red[t] = fmaxf(red[t], red[t + off]);
    __syncthreads();
  }
  const float m = red[0]; __syncthreads();
  float sm = 0.f;
  for (int j = t; j < k; j += 256) { float e = expf(lg[j] - m); lg[j] = e; sm += e; }
  red[t] = sm; __syncthreads();
  for (int off = 128; off > 0; off >>= 1) {
    if (t < off) red[t] += red[t + off];
    __syncthreads();
  }
  const float s = red[0]; __syncthreads();
  const float inv = 1.f / s;
  float ps = 0.f;
  float* orow = adj_out + ((size_t)(b * k + r)) * k;
  for (int j = t; j < k; j += 256) { float p = lg[j] * inv; orow[j] = p; ps += p; }
  red[t] = ps; __syncthreads();
  for (int off = 128; off > 0; off >>= 1) {
    if (t < off) red[t] += red[t + off];
    __syncthreads();
  }
  if (t == 0) {
    float S = red[0];
    dg[(size_t)b * k + r] = rsqrtf(fmaxf(S + 1.f, 1e-12f));
    dp[(size_t)b * k + r] = 1.f / fmaxf(S, 1.f);
  }
}

// ---------------------------------------------------------------------------
// score = rowsum |X - P| (512 cols)
// ---------------------------------------------------------------------------
__global__ __launch_bounds__(512) void absdiff_kernel(
    const float* __restrict__ X, const float* __restrict__ P, float* __restrict__ score)
{
  __shared__ float red[512];
  const int row = blockIdx.x, t = threadIdx.x;
  float d = fabsf(X[(size_t)row * 512 + t] - P[(size_t)row * 512 + t]);
  red[t] = d; __syncthreads();
  for (int off = 256; off > 0; off >>= 1) {
    if (t < off) red[t] += red[t + off];
    __syncthreads();
  }
  if (t == 0) score[row] = red[0];
}

// ---------------------------------------------------------------------------
// readout: out[b, 0:512] = colmax, out[b, 512:1024] = colmean over nrows
// ---------------------------------------------------------------------------
__global__ __launch_bounds__(512) void readout_kernel(
    const float* __restrict__ X, int nrows, float* __restrict__ out)
{
  const int b = blockIdx.x, c = threadIdx.x;
  const float* xb = X + (size_t)b * nrows * 512;
  float mx = -3.4e38f, sm = 0.f;
  for (int r = 0; r < nrows; ++r) {
    float v = xb[(size_t)r * 512 + c];
    mx = fmaxf(mx, v); sm += v;
  }
  out[(size_t)b * 1024 + c] = mx;
  out[(size_t)b * 1024 + 512 + c] = sm / (float)nrows;
}

// ---------------------------------------------------------------------------
// final MLP head + log_softmax
// ---------------------------------------------------------------------------
__global__ __launch_bounds__(512) void final_mlp_kernel(
    const float* __restrict__ r1, const float* __restrict__ r2, const float* __restrict__ r3,
    const float* __restrict__ fc1W, const float* __restrict__ fc1b,
    const float* __restrict__ fc2W, const float* __restrict__ fc2b,
    const float* __restrict__ fc3W, const float* __restrict__ fc3b,
    float* __restrict__ out)
{
  __shared__ float z[1024];
  __shared__ float z1[512];
  __shared__ float z2[256];
  __shared__ float l[2];
  const int b = blockIdx.x, t = threadIdx.x;
  for (int c = t; c < 1024; c += 512)
    z[c] = fmaxf(r1[(size_t)b * 1024 + c], 0.f) + fmaxf(r2[(size_t)b * 1024 + c], 0.f)
         + fmaxf(r3[(size_t)b * 1024 + c], 0.f);
  __syncthreads();
  {
    float acc = fc1b[t];
    for (int i = 0; i < 1024; ++i) acc = fmaf(z[i], fc1W[(size_t)i * 512 + t], acc);
    z1[t] = fmaxf(acc, 0.f);
  }
  __syncthreads();
  if (t < 256) {
    float acc = fc2b[t];
    for (int i = 0; i < 512; ++i) acc = fmaf(z1[i], fc2W[(size_t)i * 256 + t], acc);
    z2[t] = fmaxf(acc, 0.f);
  }
  __syncthreads();
  if (t < 2) {
    float acc = fc3b[t];
    for (int i = 0; i < 256; ++i) acc = fmaf(z2[i], fc3W[(size_t)i * 2 + t], acc);
    l[t] = acc;
  }
  __syncthreads();
  if (t == 0) {
    float m = fmaxf(l[0], l[1]);
    float ls = m + logf(expf(l[0] - m) + expf(l[1] - m));
    out[b * 2 + 0] = l[0] - ls;
    out[b * 2 + 1] = l[1] - ls;
  }
}

// ---------------------------------------------------------------------------
extern "C" void kernel_launch(void* const* d_in, const int* in_sizes, int n_in,
                              void* d_out, int out_size, void* d_ws, size_t ws_size,
                              hipStream_t stream)
{
  (void)in_sizes; (void)n_in; (void)out_size; (void)ws_size;
  const float* x       = (const float*)d_in[0];
  const float* adj     = (const float*)d_in[1];
  const float* lin1_W  = (const float*)d_in[2];
  const float* lin1_b  = (const float*)d_in[3];
  const float* lin2_W  = (const float*)d_in[4];
  const float* lin2_b  = (const float*)d_in[5];
  const float* conv1_W = (const float*)d_in[6];
  const float* conv1_b = (const float*)d_in[7];
  const float* conv2_W = (const float*)d_in[8];
  const float* conv2_b = (const float*)d_in[9];
  const float* conv3_W = (const float*)d_in[10];
  const float* conv3_b = (const float*)d_in[11];
  const float* att1    = (const float*)d_in[12];
  const float* att2    = (const float*)d_in[13];
  const float* fc1_W   = (const float*)d_in[14];
  const float* fc1_b   = (const float*)d_in[15];
  const float* fc2_W   = (const float*)d_in[16];
  const float* fc2_b   = (const float*)d_in[17];
  const float* fc3_W   = (const float*)d_in[18];
  const float* fc3_b   = (const float*)d_in[19];
  float* ws  = (float*)d_ws;
  float* out = (float*)d_out;

  // workspace layout (floats); aliases are safe per the liveness schedule
  float* h     = ws + 0;                       // [4,2048,544]   (dead after xw GEMM)
  float* adj1  = ws + 0;                       // [4,1024,1024]  alias over h
  float* xw    = ws + 4456448;                 // [4,2048,512]   (dead after conv1 msg)
  float* prop2 = xw;                           // [4,1024,512]   alias
  float* xk2   = ws + 4456448 + 2097152;       // [4,512,512]
  float* adj2  = ws + 4456448 + 3145728;       // [4,512,512]
  float* h1    = ws + 8650752;                 // [4,2048,512]
  float* xk1   = ws + 12845056;                // [4,1024,512]   (dead after xw2 GEMM + r1)
  float* xw3   = xk1;                          // [4,512,512]    alias
  float* h3    = ws + 12845056 + 1048576;      // [4,512,512]    alias
  float* xw2   = ws + 14942208;                // [4,1024,512]
  float* h2    = ws + 17039360;                // [4,1024,512]
  float* S     = ws + 19136512;                // small arrays
  float* dinv_g1 = S;
  float* dinv_p1 = S + 8192;
  float* score1  = S + 16384;
  int*   idx1    = (int*)(S + 24576);
  float* li1     = S + 28672;
  float* lj1     = S + 32768;
  float* r1      = S + 36864;
  float* dinv_g2 = S + 40960;
  float* dinv_p2 = S + 45056;
  float* score2  = S + 49152;
  int*   idx2    = (int*)(S + 53248);
  float* li2     = S + 55296;
  float* lj2     = S + 57344;
  float* r2      = S + 59392;
  float* dinv_g3 = S + 63488;
  float* dinv_p3 = S + 65536;
  float* r3      = S + 67584;

  // 1. lin2 -> h[:, 0:21]
  lin2_kernel<<<(4 * 2048 * 21 + 255) / 256, 256, 0, stream>>>(x, lin2_W, lin2_b, h);
  // 2. lin1 -> h[:, 21:533] : relu(x[:,21:] @ W1 + b1)
  gemm128<<<dim3(4, 64, 1), 256, 0, stream>>>(x + 21, 6165, 0, lin1_W, 512, 0,
      h + 21, 544, 0, 8192, 512, 6144, lin1_b, nullptr, nullptr, 0, 0, 1);
  // 3. degrees of adj
  degrees_kernel<<<8192, 256, 0, stream>>>(adj, dinv_g1, dinv_p1);
  // 4. xw = h @ conv1_W
  gemm128<<<dim3(4, 64, 1), 256, 0, stream>>>(h, 544, 0, conv1_W, 512, 0,
      xw, 512, 0, 8192, 512, 533, nullptr, nullptr, nullptr, 0, 0, 0);
  // 5. h1 = relu(gcn message passing) (sparse)
  conv1_msg_kernel<<<dim3(2048, 4), 256, 0, stream>>>(adj, xw, dinv_g1, conv1_b, h1);
  // 6. pool1 scores (sparse)
  pool1_score_kernel<<<dim3(2048, 4), 256, 0, stream>>>(adj, h1, dinv_p1, score1);
  // 7. top-k 2048 -> 1024
  topk_kernel<<<4, 1024, 0, stream>>>(score1, idx1, 2048, 1024);
  // 8. gather xk1, li1, lj1
  gather_li_kernel<<<dim3(1024, 4), 256, 0, stream>>>(h1, 2048, idx1, 1024, att1, xk1, li1, lj1);
  // 9. adj1 = softmax structure learning; also dinv for conv2/pool2
  slearn_kernel<<<dim3(1024, 4), 256, 0, stream>>>(adj, 2048, idx1, 1024, li1, lj1, adj1, dinv_g2, dinv_p2);
  // 10. r1 readout
  readout_kernel<<<4, 512, 0, stream>>>(xk1, 1024, r1);
  // 11. xw2 = dinv_g2 * (xk1 @ conv2_W)
  gemm128<<<dim3(4, 32, 1), 256, 0, stream>>>(xk1, 512, 0, conv2_W, 512, 0,
      xw2, 512, 0, 4096, 512, 512, nullptr, dinv_g2, nullptr, 0, 0, 0);
  // 12. h2 = relu(dinv_g2 * (adj1 @ xw2 + xw2) + b2)   [A = adj1 + I]
  gemm128<<<dim3(4, 8, 4), 256, 0, stream>>>(adj1, 1024, 1048576, xw2, 512, 524288,
      h2, 512, 524288, 1024, 512, 1024, conv2_b, dinv_g2, xw2, 524288, 512, 1);
  // 13. prop2 = dinv_p2 * (adj1 @ h2)
  gemm128<<<dim3(4, 8, 4), 256, 0, stream>>>(adj1, 1024, 1048576, h2, 512, 524288,
      prop2, 512, 524288, 1024, 512, 1024, nullptr, dinv_p2, nullptr, 0, 0, 0);
  // 14. score2
  absdiff_kernel<<<4096, 512, 0, stream>>>(h2, prop2, score2);
  // 15. top-k 1024 -> 512
  topk_kernel<<<4, 512, 0, stream>>>(score2, idx2, 1024, 512);
  // 16. gather xk2, li2, lj2
  gather_li_kernel<<<dim3(512, 4), 256, 0, stream>>>(h2, 1024, idx2, 512, att2, xk2, li2, lj2);
  // 17. adj2 + dinv for conv3
  slearn_kernel<<<dim3(512, 4), 256, 0, stream>>>(adj1, 1024, idx2, 512, li2, lj2, adj2, dinv_g3, dinv_p3);
  // 18. r2 readout
  readout_kernel<<<4, 512, 0, stream>>>(xk2, 512, r2);
  // 19. xw3 = dinv_g3 * (xk2 @ conv3_W)
  gemm128<<<dim3(4, 16, 1), 256, 0, stream>>>(xk2, 512, 0, conv3_W, 512, 0,
      xw3, 512, 0, 2048, 512, 512, nullptr, dinv_g3, nullptr, 0, 0, 0);
  // 20. h3 = relu(dinv_g3 * (adj2 @ xw3 + xw3) + b3)
  gemm128<<<dim3(4, 4, 4), 256, 0, stream>>>(adj2, 512, 262144, xw3, 512, 262144,
      h3, 512, 262144, 512, 512, 512, conv3_b, dinv_g3, xw3, 262144, 512, 1);
  // 21. r3 readout
  readout_kernel<<<4, 512, 0, stream>>>(h3, 512, r3);
  // 22. head
  final_mlp_kernel<<<4, 512, 0, stream>>>(r1, r2, r3, fc1_W, fc1_b, fc2_W, fc2_b,
                                          fc3_W, fc3_b, out);
}

// Round 2
// 1701.372 us; speedup vs baseline: 2.6662x; 2.6662x over previous
//
#include <hip/hip_runtime.h>
#include <cstdint>
#include <cstddef>

typedef __bf16 bf16x8 __attribute__((ext_vector_type(8)));
typedef float f32x4 __attribute__((ext_vector_type(4)));

// ---------------------------------------------------------------------------
// MFMA bf16x3 GEMM: C[M,N] = epilogue(A[M,K] @ B[K,N]) in ~fp32 accuracy.
// Each fp32 operand is split in-kernel to hi+lo bf16; accumulate
// a_lo*b_hi + a_hi*b_lo + a_hi*b_hi into fp32 MFMA accumulators (error ~2^-16).
// Tiles: BM=64, BN=128, BK=32. 256 threads = 4 waves; wave w owns cols
// [w*32, w*32+32) x all 64 rows = 4x2 frags of 16x16 (mfma_f32_16x16x32_bf16).
// Requirements: M % 64 == 0, N % 128 == 0; K arbitrary (guarded).
// epilogue: v = acc; if(addm) v += addm[r,c]; if(rowscale) v *= rs[r];
//           if(bias) v += bias[c]; if(relu) v = max(v,0)
// ---------------------------------------------------------------------------
#define TBM 64
#define TBN 128
#define TBK 32
#define TLD 40   // LDS k-stride (elements): 80B = 20 banks -> 2-way (free)

__global__ __launch_bounds__(256) void gemm_mfma(
    const float* __restrict__ A, long lda, long sAb,
    const float* __restrict__ B, long ldb, long sBb,
    float* __restrict__ C, long ldc, long sCb,
    int M, int N, int K,
    const float* __restrict__ bias,
    const float* __restrict__ rowscale,
    const float* __restrict__ addm, long sAddb, long ldadd,
    int do_relu)
{
  __shared__ __align__(16) __bf16 Ah[TBM * TLD];
  __shared__ __align__(16) __bf16 Al[TBM * TLD];
  __shared__ __align__(16) __bf16 Bh[TBN * TLD];  // transposed: Bh[n][k]
  __shared__ __align__(16) __bf16 Bl[TBN * TLD];

  const int bz = blockIdx.z;
  const float* Ab = A + (size_t)bz * sAb;
  const float* Bb = B + (size_t)bz * sBb;
  float* Cb = C + (size_t)bz * sCb;
  const int row0 = blockIdx.y * TBM;
  const int col0 = blockIdx.x * TBN;
  const int t = threadIdx.x;
  const int w = t >> 6, l = t & 63;
  const int lane16 = l & 15, lq = l >> 4;   // frag row/col sel, k-quarter

  f32x4 acc[4][2];
#pragma unroll
  for (int i = 0; i < 4; ++i)
#pragma unroll
    for (int j = 0; j < 2; ++j) acc[i][j] = (f32x4){0.f, 0.f, 0.f, 0.f};

  // staging roles
  const int ar = t >> 2, akq = t & 3;   // A: row (0..63), k-quarter of 8
  const int bn = t & 127, bkh = t >> 7; // B: col (0..127), k-half of 16

  for (int k0 = 0; k0 < K; k0 += TBK) {
    __syncthreads();
    // ---- stage A tile [64 x 32], split hi/lo ----
    {
      const float* src = Ab + (size_t)(row0 + ar) * lda + k0 + akq * 8;
      bf16x8 vh, vl;
#pragma unroll
      for (int i = 0; i < 8; ++i) {
        const int kg = k0 + akq * 8 + i;
        const float v = (kg < K) ? src[i] : 0.f;
        const __bf16 h = (__bf16)v;
        vh[i] = h;
        vl[i] = (__bf16)(v - (float)h);
      }
      *(bf16x8*)&Ah[ar * TLD + akq * 8] = vh;
      *(bf16x8*)&Al[ar * TLD + akq * 8] = vl;
    }
    // ---- stage B tile [32 x 128] transposed to Bs[n][k], split hi/lo ----
    {
      bf16x8 vh0, vh1, vl0, vl1;
#pragma unroll
      for (int j = 0; j < 16; ++j) {
        const int kg = k0 + bkh * 16 + j;
        const float v = (kg < K) ? Bb[(size_t)kg * ldb + col0 + bn] : 0.f;
        const __bf16 h = (__bf16)v;
        const __bf16 lo = (__bf16)(v - (float)h);
        if (j < 8) { vh0[j] = h; vl0[j] = lo; }
        else       { vh1[j - 8] = h; vl1[j - 8] = lo; }
      }
      *(bf16x8*)&Bh[bn * TLD + bkh * 16]     = vh0;
      *(bf16x8*)&Bh[bn * TLD + bkh * 16 + 8] = vh1;
      *(bf16x8*)&Bl[bn * TLD + bkh * 16]     = vl0;
      *(bf16x8*)&Bl[bn * TLD + bkh * 16 + 8] = vl1;
    }
    __syncthreads();
    // ---- compute: per-wave 4x2 fragments, bf16x3 ----
    bf16x8 a_h[4], a_l[4], b_h[2], b_l[2];
#pragma unroll
    for (int mf = 0; mf < 4; ++mf) {
      a_h[mf] = *(const bf16x8*)&Ah[(mf * 16 + lane16) * TLD + lq * 8];
      a_l[mf] = *(const bf16x8*)&Al[(mf * 16 + lane16) * TLD + lq * 8];
    }
#pragma unroll
    for (int nf = 0; nf < 2; ++nf) {
      b_h[nf] = *(const bf16x8*)&Bh[(w * 32 + nf * 16 + lane16) * TLD + lq * 8];
      b_l[nf] = *(const bf16x8*)&Bl[(w * 32 + nf * 16 + lane16) * TLD + lq * 8];
    }
#pragma unroll
    for (int mf = 0; mf < 4; ++mf)
#pragma unroll
      for (int nf = 0; nf < 2; ++nf) {
        acc[mf][nf] = __builtin_amdgcn_mfma_f32_16x16x32_bf16(a_l[mf], b_h[nf], acc[mf][nf], 0, 0, 0);
        acc[mf][nf] = __builtin_amdgcn_mfma_f32_16x16x32_bf16(a_h[mf], b_l[nf], acc[mf][nf], 0, 0, 0);
        acc[mf][nf] = __builtin_amdgcn_mfma_f32_16x16x32_bf16(a_h[mf], b_h[nf], acc[mf][nf], 0, 0, 0);
      }
  }

  // ---- epilogue: D mapping col = lane&15, row = (lane>>4)*4 + r ----
#pragma unroll
  for (int mf = 0; mf < 4; ++mf) {
#pragma unroll
    for (int r = 0; r < 4; ++r) {
      const int row = row0 + mf * 16 + lq * 4 + r;
      const float rs = rowscale ? rowscale[(size_t)bz * M + row] : 1.f;
#pragma unroll
      for (int nf = 0; nf < 2; ++nf) {
        const int col = col0 + w * 32 + nf * 16 + lane16;
        float v = acc[mf][nf][r];
        if (addm) v += addm[(size_t)bz * sAddb + (size_t)row * ldadd + col];
        v *= rs;
        if (bias) v += bias[col];
        if (do_relu) v = fmaxf(v, 0.f);
        Cb[(size_t)row * ldc + col] = v;
      }
    }
  }
}

// ---------------------------------------------------------------------------
// lin2: h[:, :, 0:21] = relu(x[:, :, 0:21] @ W2[21,21] + b2)
// ---------------------------------------------------------------------------
__global__ void lin2_kernel(const float* __restrict__ x, const float* __restrict__ W,
                            const float* __restrict__ b, float* __restrict__ h)
{
  int id = blockIdx.x * blockDim.x + threadIdx.x;
  if (id >= 4 * 2048 * 21) return;
  int row = id / 21, j = id % 21;
  const float* xr = x + (size_t)row * 6165;
  float acc = b[j];
  for (int i = 0; i < 21; ++i) acc = fmaf(xr[i], W[i * 21 + j], acc);
  h[(size_t)row * 544 + j] = fmaxf(acc, 0.f);
}

// ---------------------------------------------------------------------------
// degrees of original adj: dg = rsqrt(rowsum+1) [GCN w/ self-loop], dp = 1/max(rowsum,1) [pool]
// ---------------------------------------------------------------------------
__global__ __launch_bounds__(256) void degrees_kernel(const float* __restrict__ adj,
                                                      float* __restrict__ dg,
                                                      float* __restrict__ dp)
{
  __shared__ float red[256];
  const int row = blockIdx.x;
  const int t = threadIdx.x;
  const float* ar = adj + (size_t)row * 2048;
  float s = 0.f;
  for (int j = t; j < 2048; j += 256) s += ar[j];
  red[t] = s; __syncthreads();
  for (int off = 128; off > 0; off >>= 1) {
    if (t < off) red[t] += red[t + off];
    __syncthreads();
  }
  if (t == 0) {
    float S = red[0];
    dg[row] = rsqrtf(fmaxf(S + 1.f, 1e-12f));
    dp[row] = 1.f / fmaxf(S, 1.f);
  }
}

// ---------------------------------------------------------------------------
// conv1 message passing (sparse): out = relu(di * sum_{j in N(i)+self} a_ij*dj*xw_j + bias)
// Deterministic neighbor list: per-thread segment scan + prefix sum (no atomics).
// ---------------------------------------------------------------------------
__global__ __launch_bounds__(256) void conv1_msg_kernel(
    const float* __restrict__ adj, const float* __restrict__ xw,
    const float* __restrict__ dinv, const float* __restrict__ bias,
    float* __restrict__ out)
{
  __shared__ int nbr[2048];
  __shared__ float nval[2048];
  __shared__ int cnts[256];
  const int b = blockIdx.y, i = blockIdx.x, t = threadIdx.x;
  const float* ar = adj + ((size_t)(b * 2048 + i)) * 2048;
  int myj[8]; float myv[8]; int mc = 0;
  const int j0 = t * 8;
#pragma unroll
  for (int q = 0; q < 8; ++q) {
    float v = ar[j0 + q];
    if (v != 0.f) { myj[mc] = j0 + q; myv[mc] = v; ++mc; }
  }
  cnts[t] = mc; __syncthreads();
  for (int off = 1; off < 256; off <<= 1) {
    int v = cnts[t]; int add = (t >= off) ? cnts[t - off] : 0;
    __syncthreads();
    cnts[t] = v + add; __syncthreads();
  }
  const int base = cnts[t] - mc;
  const int total = cnts[255];
  for (int q = 0; q < mc; ++q) { nbr[base + q] = myj[q]; nval[base + q] = myv[q]; }
  __syncthreads();

  const float* xwb = xw + (size_t)b * 2048 * 512;
  const float* dv = dinv + b * 2048;
  float acc0 = 0.f, acc1 = 0.f;
  for (int n = 0; n < total; ++n) {
    const int j = nbr[n];
    const float w = nval[n] * dv[j];
    const float* xr = xwb + (size_t)j * 512;
    acc0 = fmaf(w, xr[t], acc0);
    acc1 = fmaf(w, xr[t + 256], acc1);
  }
  const float di = dv[i];
  const float* xi = xwb + (size_t)i * 512;
  acc0 = fmaf(di, xi[t], acc0);
  acc1 = fmaf(di, xi[t + 256], acc1);
  float* orow = out + ((size_t)(b * 2048 + i)) * 512;
  orow[t]       = fmaxf(di * acc0 + bias[t], 0.f);
  orow[t + 256] = fmaxf(di * acc1 + bias[t + 256], 0.f);
}

// ---------------------------------------------------------------------------
// pool1 score (sparse): score_i = sum_c | h_ic - dp_i * sum_j a_ij h_jc |
// ---------------------------------------------------------------------------
__global__ __launch_bounds__(256) void pool1_score_kernel(
    const float* __restrict__ adj, const float* __restrict__ h1,
    const float* __restrict__ dpool, float* __restrict__ score)
{
  __shared__ int nbr[2048];
  __shared__ float nval[2048];
  __shared__ int cnts[256];
  __shared__ float red[256];
  const int b = blockIdx.y, i = blockIdx.x, t = threadIdx.x;
  const float* ar = adj + ((size_t)(b * 2048 + i)) * 2048;
  int myj[8]; float myv[8]; int mc = 0;
  const int j0 = t * 8;
#pragma unroll
  for (int q = 0; q < 8; ++q) {
    float v = ar[j0 + q];
    if (v != 0.f) { myj[mc] = j0 + q; myv[mc] = v; ++mc; }
  }
  cnts[t] = mc; __syncthreads();
  for (int off = 1; off < 256; off <<= 1) {
    int v = cnts[t]; int add = (t >= off) ? cnts[t - off] : 0;
    __syncthreads();
    cnts[t] = v + add; __syncthreads();
  }
  const int base = cnts[t] - mc;
  const int total = cnts[255];
  for (int q = 0; q < mc; ++q) { nbr[base + q] = myj[q]; nval[base + q] = myv[q]; }
  __syncthreads();

  const float* hb = h1 + (size_t)b * 2048 * 512;
  float acc0 = 0.f, acc1 = 0.f;
  for (int n = 0; n < total; ++n) {
    const int j = nbr[n];
    const float w = nval[n];
    const float* xr = hb + (size_t)j * 512;
    acc0 = fmaf(w, xr[t], acc0);
    acc1 = fmaf(w, xr[t + 256], acc1);
  }
  const float dpi = dpool[b * 2048 + i];
  const float* hi = hb + (size_t)i * 512;
  float part = fabsf(hi[t] - dpi * acc0) + fabsf(hi[t + 256] - dpi * acc1);
  red[t] = part; __syncthreads();
  for (int off = 128; off > 0; off >>= 1) {
    if (t < off) red[t] += red[t + off];
    __syncthreads();
  }
  if (t == 0) score[b * 2048 + i] = red[0];
}

// ---------------------------------------------------------------------------
// top-k: full bitonic sort of (score,~idx) packed u64 keys (descending), take
// first k indices, bitonic-sort them ascending. blockDim must be n/2 (== k).
// ---------------------------------------------------------------------------
__global__ __launch_bounds__(1024) void topk_kernel(
    const float* __restrict__ score, int* __restrict__ idx_out, int n, int k)
{
  __shared__ unsigned long long key[2048];
  const unsigned b = blockIdx.x, t = threadIdx.x;
  const unsigned bd = blockDim.x;  // n/2
  for (unsigned i = t; i < (unsigned)n; i += bd) {
    unsigned u = __float_as_uint(score[(size_t)b * n + i]);  // scores >= 0 -> monotone
    key[i] = ((unsigned long long)u << 32) | (unsigned)(~i);
  }
  __syncthreads();
  for (unsigned size = 2; size <= (unsigned)n; size <<= 1) {
    for (unsigned stride = size >> 1; stride > 0; stride >>= 1) {
      const unsigned i = (t / stride) * (stride * 2) + (t % stride);
      const unsigned ixj = i + stride;
      const bool up = ((i & size) == 0);
      unsigned long long a = key[i], c = key[ixj];
      if (up ? (a < c) : (a > c)) { key[i] = c; key[ixj] = a; }
      __syncthreads();
    }
  }
  // t < bd == k: extract selected indices
  const unsigned my = ~(unsigned)(key[t] & 0xFFFFFFFFull);
  __syncthreads();
  unsigned* arr = (unsigned*)key;
  arr[t] = my;
  __syncthreads();
  for (unsigned size = 2; size <= (unsigned)k; size <<= 1) {
    for (unsigned stride = size >> 1; stride > 0; stride >>= 1) {
      if (t < (unsigned)k / 2) {
        const unsigned i = (t / stride) * (stride * 2) + (t % stride);
        const unsigned ixj = i + stride;
        const bool up = ((i & size) == 0);
        unsigned a = arr[i], c = arr[ixj];
        if (up ? (a > c) : (a < c)) { arr[i] = c; arr[ixj] = a; }
      }
      __syncthreads();
    }
  }
  idx_out[(size_t)b * k + t] = (int)arr[t];
}

// ---------------------------------------------------------------------------
// gather pooled rows + li/lj attention dots
// ---------------------------------------------------------------------------
__global__ __launch_bounds__(256) void gather_li_kernel(
    const float* __restrict__ X, int src_n,
    const int* __restrict__ idx, int k,
    const float* __restrict__ att,
    float* __restrict__ xk, float* __restrict__ li, float* __restrict__ lj)
{
  __shared__ float redA[256], redB[256];
  const int b = blockIdx.y, r = blockIdx.x, t = threadIdx.x;
  const int g = idx[(size_t)b * k + r];
  const float* src = X + ((size_t)(b * src_n + g)) * 512;
  float* dst = xk + ((size_t)(b * k + r)) * 512;
  const float v0 = src[t], v1 = src[t + 256];
  dst[t] = v0; dst[t + 256] = v1;
  redA[t] = v0 * att[t] + v1 * att[t + 256];
  redB[t] = v0 * att[512 + t] + v1 * att[512 + t + 256];
  __syncthreads();
  for (int off = 128; off > 0; off >>= 1) {
    if (t < off) { redA[t] += redA[t + off]; redB[t] += redB[t + off]; }
    __syncthreads();
  }
  if (t == 0) { li[(size_t)b * k + r] = redA[0]; lj[(size_t)b * k + r] = redB[0]; }
}

// ---------------------------------------------------------------------------
// structure learning: adj_out[r,:] = softmax(li_r + lj_j + Asrc[gi,gj]); also
// emits GCN dinv (rsqrt(rowsum+1)) and pool dinv (1/max(rowsum,1)) of adj_out.
// ---------------------------------------------------------------------------
__global__ __launch_bounds__(256) void slearn_kernel(
    const float* __restrict__ Asrc, int src_n,
    const int* __restrict__ idx, int k,
    const float* __restrict__ li, const float* __restrict__ lj,
    float* __restrict__ adj_out, float* __restrict__ dg, float* __restrict__ dp)
{
  __shared__ int gidx[1024];
  __shared__ float ljv[1024];
  __shared__ float lg[1024];
  __shared__ float red[256];
  const int b = blockIdx.y, r = blockIdx.x, t = threadIdx.x;
  for (int j = t; j < k; j += 256) { gidx[j] = idx[(size_t)b * k + j]; ljv[j] = lj[(size_t)b * k + j]; }
  __syncthreads();
  const int gi = gidx[r];
  const float lir = li[(size_t)b * k + r];
  const float* ar = Asrc + ((size_t)(b * src_n + gi)) * src_n;
  float mx = -3.4e38f;
  for (int j = t; j < k; j += 256) {
    float v = lir + ljv[j] + ar[gidx[j]];   // LAMB = 1.0
    lg[j] = v; mx = fmaxf(mx, v);
  }
  red[t] = mx; __syncthreads();
  for (int off = 128; off > 0; off >>= 1) {
    if (t < off) red[t] = fmaxf(red[t], red[t + off]);
    __syncthreads();
  }
  const float m = red[0]; __syncthreads();
  float sm = 0.f;
  for (int j = t; j < k; j += 256) { float e = expf(lg[j] - m); lg[j] = e; sm += e; }
  red[t] = sm; __syncthreads();
  for (int off = 128; off > 0; off >>= 1) {
    if (t < off) red[t] += red[t + off];
    __syncthreads();
  }
  const float s = red[0]; __syncthreads();
  const float inv = 1.f / s;
  float ps = 0.f;
  float* orow = adj_out + ((size_t)(b * k + r)) * k;
  for (int j = t; j < k; j += 256) { float p = lg[j] * inv; orow[j] = p; ps += p; }
  red[t] = ps; __syncthreads();
  for (int off = 128; off > 0; off >>= 1) {
    if (t < off) red[t] += red[t + off];
    __syncthreads();
  }
  if (t == 0) {
    float S = red[0];
    dg[(size_t)b * k + r] = rsqrtf(fmaxf(S + 1.f, 1e-12f));
    dp[(size_t)b * k + r] = 1.f / fmaxf(S, 1.f);
  }
}

// ---------------------------------------------------------------------------
// score = rowsum |X - P| (512 cols)
// ---------------------------------------------------------------------------
__global__ __launch_bounds__(512) void absdiff_kernel(
    const float* __restrict__ X, const float* __restrict__ P, float* __restrict__ score)
{
  __shared__ float red[512];
  const int row = blockIdx.x, t = threadIdx.x;
  float d = fabsf(X[(size_t)row * 512 + t] - P[(size_t)row * 512 + t]);
  red[t] = d; __syncthreads();
  for (int off = 256; off > 0; off >>= 1) {
    if (t < off) red[t] += red[t + off];
    __syncthreads();
  }
  if (t == 0) score[row] = red[0];
}

// ---------------------------------------------------------------------------
// readout: out[b, 0:512] = colmax, out[b, 512:1024] = colmean over nrows
// ---------------------------------------------------------------------------
__global__ __launch_bounds__(512) void readout_kernel(
    const float* __restrict__ X, int nrows, float* __restrict__ out)
{
  const int b = blockIdx.x, c = threadIdx.x;
  const float* xb = X + (size_t)b * nrows * 512;
  float mx = -3.4e38f, sm = 0.f;
  for (int r = 0; r < nrows; ++r) {
    float v = xb[(size_t)r * 512 + c];
    mx = fmaxf(mx, v); sm += v;
  }
  out[(size_t)b * 1024 + c] = mx;
  out[(size_t)b * 1024 + 512 + c] = sm / (float)nrows;
}

// ---------------------------------------------------------------------------
// final MLP head + log_softmax
// ---------------------------------------------------------------------------
__global__ __launch_bounds__(512) void final_mlp_kernel(
    const float* __restrict__ r1, const float* __restrict__ r2, const float* __restrict__ r3,
    const float* __restrict__ fc1W, const float* __restrict__ fc1b,
    const float* __restrict__ fc2W, const float* __restrict__ fc2b,
    const float* __restrict__ fc3W, const float* __restrict__ fc3b,
    float* __restrict__ out)
{
  __shared__ float z[1024];
  __shared__ float z1[512];
  __shared__ float z2[256];
  __shared__ float l[2];
  const int b = blockIdx.x, t = threadIdx.x;
  for (int c = t; c < 1024; c += 512)
    z[c] = fmaxf(r1[(size_t)b * 1024 + c], 0.f) + fmaxf(r2[(size_t)b * 1024 + c], 0.f)
         + fmaxf(r3[(size_t)b * 1024 + c], 0.f);
  __syncthreads();
  {
    float acc = fc1b[t];
    for (int i = 0; i < 1024; ++i) acc = fmaf(z[i], fc1W[(size_t)i * 512 + t], acc);
    z1[t] = fmaxf(acc, 0.f);
  }
  __syncthreads();
  if (t < 256) {
    float acc = fc2b[t];
    for (int i = 0; i < 512; ++i) acc = fmaf(z1[i], fc2W[(size_t)i * 256 + t], acc);
    z2[t] = fmaxf(acc, 0.f);
  }
  __syncthreads();
  if (t < 2) {
    float acc = fc3b[t];
    for (int i = 0; i < 256; ++i) acc = fmaf(z2[i], fc3W[(size_t)i * 2 + t], acc);
    l[t] = acc;
  }
  __syncthreads();
  if (t == 0) {
    float m = fmaxf(l[0], l[1]);
    float ls = m + logf(expf(l[0] - m) + expf(l[1] - m));
    out[b * 2 + 0] = l[0] - ls;
    out[b * 2 + 1] = l[1] - ls;
  }
}

// ---------------------------------------------------------------------------
extern "C" void kernel_launch(void* const* d_in, const int* in_sizes, int n_in,
                              void* d_out, int out_size, void* d_ws, size_t ws_size,
                              hipStream_t stream)
{
  (void)in_sizes; (void)n_in; (void)out_size; (void)ws_size;
  const float* x       = (const float*)d_in[0];
  const float* adj     = (const float*)d_in[1];
  const float* lin1_W  = (const float*)d_in[2];
  const float* lin1_b  = (const float*)d_in[3];
  const float* lin2_W  = (const float*)d_in[4];
  const float* lin2_b  = (const float*)d_in[5];
  const float* conv1_W = (const float*)d_in[6];
  const float* conv1_b = (const float*)d_in[7];
  const float* conv2_W = (const float*)d_in[8];
  const float* conv2_b = (const float*)d_in[9];
  const float* conv3_W = (const float*)d_in[10];
  const float* conv3_b = (const float*)d_in[11];
  const float* att1    = (const float*)d_in[12];
  const float* att2    = (const float*)d_in[13];
  const float* fc1_W   = (const float*)d_in[14];
  const float* fc1_b   = (const float*)d_in[15];
  const float* fc2_W   = (const float*)d_in[16];
  const float* fc2_b   = (const float*)d_in[17];
  const float* fc3_W   = (const float*)d_in[18];
  const float* fc3_b   = (const float*)d_in[19];
  float* ws  = (float*)d_ws;
  float* out = (float*)d_out;

  // workspace layout (floats); aliases are safe per the liveness schedule
  float* h     = ws + 0;                       // [4,2048,544]   (dead after xw GEMM)
  float* adj1  = ws + 0;                       // [4,1024,1024]  alias over h
  float* xw    = ws + 4456448;                 // [4,2048,512]   (dead after conv1 msg)
  float* prop2 = xw;                           // [4,1024,512]   alias
  float* xk2   = ws + 4456448 + 2097152;       // [4,512,512]
  float* adj2  = ws + 4456448 + 3145728;       // [4,512,512]
  float* h1    = ws + 8650752;                 // [4,2048,512]
  float* xk1   = ws + 12845056;                // [4,1024,512]   (dead after xw2 GEMM + r1)
  float* xw3   = xk1;                          // [4,512,512]    alias
  float* h3    = ws + 12845056 + 1048576;      // [4,512,512]    alias
  float* xw2   = ws + 14942208;                // [4,1024,512]
  float* h2    = ws + 17039360;                // [4,1024,512]
  float* S     = ws + 19136512;                // small arrays
  float* dinv_g1 = S;
  float* dinv_p1 = S + 8192;
  float* score1  = S + 16384;
  int*   idx1    = (int*)(S + 24576);
  float* li1     = S + 28672;
  float* lj1     = S + 32768;
  float* r1      = S + 36864;
  float* dinv_g2 = S + 40960;
  float* dinv_p2 = S + 45056;
  float* score2  = S + 49152;
  int*   idx2    = (int*)(S + 53248);
  float* li2     = S + 55296;
  float* lj2     = S + 57344;
  float* r2      = S + 59392;
  float* dinv_g3 = S + 63488;
  float* dinv_p3 = S + 65536;
  float* r3      = S + 67584;

  // 1. lin2 -> h[:, 0:21]
  lin2_kernel<<<(4 * 2048 * 21 + 255) / 256, 256, 0, stream>>>(x, lin2_W, lin2_b, h);
  // 2. lin1 -> h[:, 21:533] : relu(x[:,21:] @ W1 + b1)
  gemm_mfma<<<dim3(4, 128, 1), 256, 0, stream>>>(x + 21, 6165, 0, lin1_W, 512, 0,
      h + 21, 544, 0, 8192, 512, 6144, lin1_b, nullptr, nullptr, 0, 0, 1);
  // 3. degrees of adj
  degrees_kernel<<<8192, 256, 0, stream>>>(adj, dinv_g1, dinv_p1);
  // 4. xw = h @ conv1_W
  gemm_mfma<<<dim3(4, 128, 1), 256, 0, stream>>>(h, 544, 0, conv1_W, 512, 0,
      xw, 512, 0, 8192, 512, 533, nullptr, nullptr, nullptr, 0, 0, 0);
  // 5. h1 = relu(gcn message passing) (sparse)
  conv1_msg_kernel<<<dim3(2048, 4), 256, 0, stream>>>(adj, xw, dinv_g1, conv1_b, h1);
  // 6. pool1 scores (sparse)
  pool1_score_kernel<<<dim3(2048, 4), 256, 0, stream>>>(adj, h1, dinv_p1, score1);
  // 7. top-k 2048 -> 1024
  topk_kernel<<<4, 1024, 0, stream>>>(score1, idx1, 2048, 1024);
  // 8. gather xk1, li1, lj1
  gather_li_kernel<<<dim3(1024, 4), 256, 0, stream>>>(h1, 2048, idx1, 1024, att1, xk1, li1, lj1);
  // 9. adj1 = softmax structure learning; also dinv for conv2/pool2
  slearn_kernel<<<dim3(1024, 4), 256, 0, stream>>>(adj, 2048, idx1, 1024, li1, lj1, adj1, dinv_g2, dinv_p2);
  // 10. r1 readout
  readout_kernel<<<4, 512, 0, stream>>>(xk1, 1024, r1);
  // 11. xw2 = dinv_g2 * (xk1 @ conv2_W)
  gemm_mfma<<<dim3(4, 64, 1), 256, 0, stream>>>(xk1, 512, 0, conv2_W, 512, 0,
      xw2, 512, 0, 4096, 512, 512, nullptr, dinv_g2, nullptr, 0, 0, 0);
  // 12. h2 = relu(dinv_g2 * (adj1 @ xw2 + xw2) + b2)   [A = adj1 + I]
  gemm_mfma<<<dim3(4, 16, 4), 256, 0, stream>>>(adj1, 1024, 1048576, xw2, 512, 524288,
      h2, 512, 524288, 1024, 512, 1024, conv2_b, dinv_g2, xw2, 524288, 512, 1);
  // 13. prop2 = dinv_p2 * (adj1 @ h2)
  gemm_mfma<<<dim3(4, 16, 4), 256, 0, stream>>>(adj1, 1024, 1048576, h2, 512, 524288,
      prop2, 512, 524288, 1024, 512, 1024, nullptr, dinv_p2, nullptr, 0, 0, 0);
  // 14. score2
  absdiff_kernel<<<4096, 512, 0, stream>>>(h2, prop2, score2);
  // 15. top-k 1024 -> 512
  topk_kernel<<<4, 512, 0, stream>>>(score2, idx2, 1024, 512);
  // 16. gather xk2, li2, lj2
  gather_li_kernel<<<dim3(512, 4), 256, 0, stream>>>(h2, 1024, idx2, 512, att2, xk2, li2, lj2);
  // 17. adj2 + dinv for conv3
  slearn_kernel<<<dim3(512, 4), 256, 0, stream>>>(adj1, 1024, idx2, 512, li2, lj2, adj2, dinv_g3, dinv_p3);
  // 18. r2 readout
  readout_kernel<<<4, 512, 0, stream>>>(xk2, 512, r2);
  // 19. xw3 = dinv_g3 * (xk2 @ conv3_W)
  gemm_mfma<<<dim3(4, 32, 1), 256, 0, stream>>>(xk2, 512, 0, conv3_W, 512, 0,
      xw3, 512, 0, 2048, 512, 512, nullptr, dinv_g3, nullptr, 0, 0, 0);
  // 20. h3 = relu(dinv_g3 * (adj2 @ xw3 + xw3) + b3)
  gemm_mfma<<<dim3(4, 8, 4), 256, 0, stream>>>(adj2, 512, 262144, xw3, 512, 262144,
      h3, 512, 262144, 512, 512, 512, conv3_b, dinv_g3, xw3, 262144, 512, 1);
  // 21. r3 readout
  readout_kernel<<<4, 512, 0, stream>>>(h3, 512, r3);
  // 22. head
  final_mlp_kernel<<<4, 512, 0, stream>>>(r1, r2, r3, fc1_W, fc1_b, fc2_W, fc2_b,
                                          fc3_W, fc3_b, out);
}

// Round 3
// 1397.658 us; speedup vs baseline: 3.2456x; 1.2173x over previous
//
#include <hip/hip_runtime.h>
#include <cstdint>
#include <cstddef>

typedef __bf16 bf16x8 __attribute__((ext_vector_type(8)));
typedef float f32x4 __attribute__((ext_vector_type(4)));

// ---------------------------------------------------------------------------
// MFMA bf16x3 GEMM v2: C[M,N] = epilogue(A[M,K] @ B[K,N]) at ~fp32 accuracy.
//  - A: fp32, split hi/lo bf16 in-kernel during staging.
//  - B: PRE-split + PRE-transposed bf16 arrays BtH/BtL of shape [N][ldbt].
//  - LDS in fragment order (ds_read/write = base + lane*16 -> conflict-free).
//  - Register-staged double buffer, one barrier per K-tile.
//  - XCD-aware bijective block swizzle (same-col blocks share an XCD's L2).
// Tiles BM=64, BN=128, BK=32; 256 threads = 4 waves; wave w owns cols
// [w*32,w*32+32) x 64 rows = 4mf x 2nf frags of mfma_f32_16x16x32_bf16 (x3).
// Requirements: M%64==0, N%128==0, K%32==0 (pad inputs to satisfy).
// epilogue: v = acc; if(addm) v += addm[r,c]; if(rowscale) v *= rs[r];
//           if(bias) v += bias[c]; if(relu) v = max(v,0)
// ---------------------------------------------------------------------------
#define TBM 64
#define TBN 128
#define TBK 32
#define LDS_BUF 24576   // bytes per buffer: A hi/lo 4KB+4KB, B hi/lo 8KB+8KB

__global__ __launch_bounds__(256) void gemm_mfma(
    const float* __restrict__ A, long lda, long sAb,
    const __bf16* __restrict__ BtH, const __bf16* __restrict__ BtL, long ldbt, long sBtb,
    float* __restrict__ C, long ldc, long sCb,
    int M, int N, int K,
    const float* __restrict__ bias,
    const float* __restrict__ rowscale,
    const float* __restrict__ addm, long sAddb, long ldadd,
    int do_relu)
{
  __shared__ __align__(16) char smem[2 * LDS_BUF];

  const int bz = blockIdx.z;
  const float* Ab = A + (size_t)bz * sAb;
  const __bf16* BHb = BtH + (size_t)bz * sBtb;
  const __bf16* BLb = BtL + (size_t)bz * sBtb;
  float* Cb = C + (size_t)bz * sCb;

  // XCD-aware bijective swizzle: blocks with the same col0 cluster per XCD.
  int flat = blockIdx.y * gridDim.x + blockIdx.x;
  const int nwg = gridDim.x * gridDim.y;
  if ((nwg & 7) == 0) { const int q = nwg >> 3; flat = (flat & 7) * q + (flat >> 3); }
  const int col0 = (flat / gridDim.y) * TBN;
  const int row0 = (flat % gridDim.y) * TBM;

  const int t = threadIdx.x;
  const int w = t >> 6, l = t & 63;
  const int l16 = l & 15, lq = l >> 4;

  // staging roles
  const int s_row = t >> 2, s_oct = t & 3;    // A: 8 consecutive floats
  const int s_col = t & 127, s_kh = t >> 7;   // B: 16 bf16 (one k-half)
  const int a_off  = ((s_row >> 4) * 64 + s_oct * 16 + (s_row & 15)) * 16;
  const int b_off0 = ((s_col >> 4) * 64 + (s_kh * 2) * 16 + (s_col & 15)) * 16;

  const float*  aptr = Ab + (size_t)(row0 + s_row) * lda + s_oct * 8;
  const __bf16* bhp  = BHb + (size_t)(col0 + s_col) * ldbt + s_kh * 16;
  const __bf16* blp  = BLb + (size_t)(col0 + s_col) * ldbt + s_kh * 16;

  f32x4 acc[4][2];
#pragma unroll
  for (int i = 0; i < 4; ++i)
#pragma unroll
    for (int j = 0; j < 2; ++j) acc[i][j] = (f32x4){0.f, 0.f, 0.f, 0.f};

  float ar[8];
  bf16x8 brh0, brh1, brl0, brl1;

#define G_LOAD(K0)                                                         \
  {                                                                        \
    const float* ap = aptr + (K0);                                         \
    _Pragma("unroll")                                                      \
    for (int i = 0; i < 8; ++i) ar[i] = ap[i];                             \
    brh0 = *(const bf16x8*)(bhp + (K0));                                   \
    brh1 = *(const bf16x8*)(bhp + (K0) + 8);                               \
    brl0 = *(const bf16x8*)(blp + (K0));                                   \
    brl1 = *(const bf16x8*)(blp + (K0) + 8);                               \
  }

#define L_WRITE(BUF)                                                       \
  {                                                                        \
    char* wb = smem + (BUF) * LDS_BUF;                                     \
    bf16x8 vh, vl;                                                         \
    _Pragma("unroll")                                                      \
    for (int i = 0; i < 8; ++i) {                                          \
      const __bf16 hh = (__bf16)ar[i];                                     \
      vh[i] = hh; vl[i] = (__bf16)(ar[i] - (float)hh);                     \
    }                                                                      \
    *(bf16x8*)(wb + a_off) = vh;                                           \
    *(bf16x8*)(wb + 4096 + a_off) = vl;                                    \
    *(bf16x8*)(wb + 8192  + b_off0) = brh0;                                \
    *(bf16x8*)(wb + 8192  + b_off0 + 256) = brh1;                          \
    *(bf16x8*)(wb + 16384 + b_off0) = brl0;                                \
    *(bf16x8*)(wb + 16384 + b_off0 + 256) = brl1;                          \
  }

  const int T = K >> 5;
  G_LOAD(0);
  L_WRITE(0);
  __syncthreads();

  for (int kt = 0; kt < T; ++kt) {
    const bool more = (kt + 1 < T);
    if (more) G_LOAD((kt + 1) << 5);

    const char* rb = smem + (kt & 1) * LDS_BUF;
    bf16x8 fah[4], fal[4], fbh[2], fbl[2];
#pragma unroll
    for (int mf = 0; mf < 4; ++mf) {
      fah[mf] = *(const bf16x8*)(rb + mf * 1024 + l * 16);
      fal[mf] = *(const bf16x8*)(rb + 4096 + mf * 1024 + l * 16);
    }
#pragma unroll
    for (int nf = 0; nf < 2; ++nf) {
      const int nfg = w * 2 + nf;
      fbh[nf] = *(const bf16x8*)(rb + 8192 + nfg * 1024 + l * 16);
      fbl[nf] = *(const bf16x8*)(rb + 16384 + nfg * 1024 + l * 16);
    }
#pragma unroll
    for (int mf = 0; mf < 4; ++mf)
#pragma unroll
      for (int nf = 0; nf < 2; ++nf) {
        acc[mf][nf] = __builtin_amdgcn_mfma_f32_16x16x32_bf16(fal[mf], fbh[nf], acc[mf][nf], 0, 0, 0);
        acc[mf][nf] = __builtin_amdgcn_mfma_f32_16x16x32_bf16(fah[mf], fbl[nf], acc[mf][nf], 0, 0, 0);
        acc[mf][nf] = __builtin_amdgcn_mfma_f32_16x16x32_bf16(fah[mf], fbh[nf], acc[mf][nf], 0, 0, 0);
      }

    if (more) {
      L_WRITE((kt + 1) & 1);
      __syncthreads();
    }
  }
#undef G_LOAD
#undef L_WRITE

  // epilogue: D mapping col = lane&15, row = (lane>>4)*4 + r
#pragma unroll
  for (int mf = 0; mf < 4; ++mf) {
#pragma unroll
    for (int r = 0; r < 4; ++r) {
      const int row = row0 + mf * 16 + lq * 4 + r;
      const float rs = rowscale ? rowscale[(size_t)bz * M + row] : 1.f;
#pragma unroll
      for (int nf = 0; nf < 2; ++nf) {
        const int col = col0 + w * 32 + nf * 16 + l16;
        float v = acc[mf][nf][r];
        if (addm) v += addm[(size_t)bz * sAddb + (size_t)row * ldadd + col];
        v *= rs;
        if (bias) v += bias[col];
        if (do_relu) v = fmaxf(v, 0.f);
        Cb[(size_t)row * ldc + col] = v;
      }
    }
  }
}

// ---------------------------------------------------------------------------
// split-transpose: in fp32 [Kin][Nin] -> outH/outL bf16 [Nin][Kp] (zero-pad
// rows Kin..Kp). Block (32,8) does a 32x32 tile via LDS. Nin % 32 == 0.
// ---------------------------------------------------------------------------
__global__ __launch_bounds__(256) void split_transpose_kernel(
    const float* __restrict__ in, long sInb, int Kin, int Nin,
    __bf16* __restrict__ outH, __bf16* __restrict__ outL, long sOutb, int Kp)
{
  __shared__ float tile[32][33];
  const int n0 = blockIdx.x * 32, k0 = blockIdx.y * 32, b = blockIdx.z;
  const float* src = in + (size_t)b * sInb;
  const int tx = threadIdx.x, ty = threadIdx.y;
#pragma unroll
  for (int r = 0; r < 4; ++r) {
    const int k = k0 + ty + r * 8;
    tile[ty + r * 8][tx] = (k < Kin) ? src[(size_t)k * Nin + n0 + tx] : 0.f;
  }
  __syncthreads();
#pragma unroll
  for (int r = 0; r < 4; ++r) {
    const int n = n0 + ty + r * 8;
    const int k = k0 + tx;
    const float v = tile[tx][ty + r * 8];
    const __bf16 h = (__bf16)v;
    outH[(size_t)b * sOutb + (size_t)n * Kp + k] = h;
    outL[(size_t)b * sOutb + (size_t)n * Kp + k] = (__bf16)(v - (float)h);
  }
}

// ---------------------------------------------------------------------------
// lin2: h[:, :, 0:21] = relu(x[:, :, 0:21] @ W2[21,21] + b2)
// ---------------------------------------------------------------------------
__global__ void lin2_kernel(const float* __restrict__ x, const float* __restrict__ W,
                            const float* __restrict__ b, float* __restrict__ h)
{
  int id = blockIdx.x * blockDim.x + threadIdx.x;
  if (id >= 4 * 2048 * 21) return;
  int row = id / 21, j = id % 21;
  const float* xr = x + (size_t)row * 6165;
  float acc = b[j];
  for (int i = 0; i < 21; ++i) acc = fmaf(xr[i], W[i * 21 + j], acc);
  h[(size_t)row * 544 + j] = fmaxf(acc, 0.f);
}

// zero pad columns 533..544 of h so the xw GEMM can run guard-free at K=544
__global__ void pad_h_kernel(float* __restrict__ h)
{
  int id = blockIdx.x * blockDim.x + threadIdx.x;
  if (id >= 4 * 2048 * 11) return;
  int row = id / 11, c = 533 + id % 11;
  h[(size_t)row * 544 + c] = 0.f;
}

// ---------------------------------------------------------------------------
// degrees of original adj: dg = rsqrt(rowsum+1) [GCN w/ self-loop], dp = 1/max(rowsum,1)
// ---------------------------------------------------------------------------
__global__ __launch_bounds__(256) void degrees_kernel(const float* __restrict__ adj,
                                                      float* __restrict__ dg,
                                                      float* __restrict__ dp)
{
  __shared__ float red[256];
  const int row = blockIdx.x;
  const int t = threadIdx.x;
  const float* ar = adj + (size_t)row * 2048;
  float s = 0.f;
  for (int j = t; j < 2048; j += 256) s += ar[j];
  red[t] = s; __syncthreads();
  for (int off = 128; off > 0; off >>= 1) {
    if (t < off) red[t] += red[t + off];
    __syncthreads();
  }
  if (t == 0) {
    float S = red[0];
    dg[row] = rsqrtf(fmaxf(S + 1.f, 1e-12f));
    dp[row] = 1.f / fmaxf(S, 1.f);
  }
}

// ---------------------------------------------------------------------------
// conv1 message passing (sparse)
// ---------------------------------------------------------------------------
__global__ __launch_bounds__(256) void conv1_msg_kernel(
    const float* __restrict__ adj, const float* __restrict__ xw,
    const float* __restrict__ dinv, const float* __restrict__ bias,
    float* __restrict__ out)
{
  __shared__ int nbr[2048];
  __shared__ float nval[2048];
  __shared__ int cnts[256];
  const int b = blockIdx.y, i = blockIdx.x, t = threadIdx.x;
  const float* ar = adj + ((size_t)(b * 2048 + i)) * 2048;
  int myj[8]; float myv[8]; int mc = 0;
  const int j0 = t * 8;
#pragma unroll
  for (int q = 0; q < 8; ++q) {
    float v = ar[j0 + q];
    if (v != 0.f) { myj[mc] = j0 + q; myv[mc] = v; ++mc; }
  }
  cnts[t] = mc; __syncthreads();
  for (int off = 1; off < 256; off <<= 1) {
    int v = cnts[t]; int add = (t >= off) ? cnts[t - off] : 0;
    __syncthreads();
    cnts[t] = v + add; __syncthreads();
  }
  const int base = cnts[t] - mc;
  const int total = cnts[255];
  for (int q = 0; q < mc; ++q) { nbr[base + q] = myj[q]; nval[base + q] = myv[q]; }
  __syncthreads();

  const float* xwb = xw + (size_t)b * 2048 * 512;
  const float* dv = dinv + b * 2048;
  float acc0 = 0.f, acc1 = 0.f;
  for (int n = 0; n < total; ++n) {
    const int j = nbr[n];
    const float w = nval[n] * dv[j];
    const float* xr = xwb + (size_t)j * 512;
    acc0 = fmaf(w, xr[t], acc0);
    acc1 = fmaf(w, xr[t + 256], acc1);
  }
  const float di = dv[i];
  const float* xi = xwb + (size_t)i * 512;
  acc0 = fmaf(di, xi[t], acc0);
  acc1 = fmaf(di, xi[t + 256], acc1);
  float* orow = out + ((size_t)(b * 2048 + i)) * 512;
  orow[t]       = fmaxf(di * acc0 + bias[t], 0.f);
  orow[t + 256] = fmaxf(di * acc1 + bias[t + 256], 0.f);
}

// ---------------------------------------------------------------------------
// pool1 score (sparse): score_i = sum_c | h_ic - dp_i * sum_j a_ij h_jc |
// ---------------------------------------------------------------------------
__global__ __launch_bounds__(256) void pool1_score_kernel(
    const float* __restrict__ adj, const float* __restrict__ h1,
    const float* __restrict__ dpool, float* __restrict__ score)
{
  __shared__ int nbr[2048];
  __shared__ float nval[2048];
  __shared__ int cnts[256];
  __shared__ float red[256];
  const int b = blockIdx.y, i = blockIdx.x, t = threadIdx.x;
  const float* ar = adj + ((size_t)(b * 2048 + i)) * 2048;
  int myj[8]; float myv[8]; int mc = 0;
  const int j0 = t * 8;
#pragma unroll
  for (int q = 0; q < 8; ++q) {
    float v = ar[j0 + q];
    if (v != 0.f) { myj[mc] = j0 + q; myv[mc] = v; ++mc; }
  }
  cnts[t] = mc; __syncthreads();
  for (int off = 1; off < 256; off <<= 1) {
    int v = cnts[t]; int add = (t >= off) ? cnts[t - off] : 0;
    __syncthreads();
    cnts[t] = v + add; __syncthreads();
  }
  const int base = cnts[t] - mc;
  const int total = cnts[255];
  for (int q = 0; q < mc; ++q) { nbr[base + q] = myj[q]; nval[base + q] = myv[q]; }
  __syncthreads();

  const float* hb = h1 + (size_t)b * 2048 * 512;
  float acc0 = 0.f, acc1 = 0.f;
  for (int n = 0; n < total; ++n) {
    const int j = nbr[n];
    const float w = nval[n];
    const float* xr = hb + (size_t)j * 512;
    acc0 = fmaf(w, xr[t], acc0);
    acc1 = fmaf(w, xr[t + 256], acc1);
  }
  const float dpi = dpool[b * 2048 + i];
  const float* hi = hb + (size_t)i * 512;
  float part = fabsf(hi[t] - dpi * acc0) + fabsf(hi[t + 256] - dpi * acc1);
  red[t] = part; __syncthreads();
  for (int off = 128; off > 0; off >>= 1) {
    if (t < off) red[t] += red[t + off];
    __syncthreads();
  }
  if (t == 0) score[b * 2048 + i] = red[0];
}

// ---------------------------------------------------------------------------
// top-k via full bitonic sort of (score,~idx) packed u64 keys
// ---------------------------------------------------------------------------
__global__ __launch_bounds__(1024) void topk_kernel(
    const float* __restrict__ score, int* __restrict__ idx_out, int n, int k)
{
  __shared__ unsigned long long key[2048];
  const unsigned b = blockIdx.x, t = threadIdx.x;
  const unsigned bd = blockDim.x;  // n/2
  for (unsigned i = t; i < (unsigned)n; i += bd) {
    unsigned u = __float_as_uint(score[(size_t)b * n + i]);
    key[i] = ((unsigned long long)u << 32) | (unsigned)(~i);
  }
  __syncthreads();
  for (unsigned size = 2; size <= (unsigned)n; size <<= 1) {
    for (unsigned stride = size >> 1; stride > 0; stride >>= 1) {
      const unsigned i = (t / stride) * (stride * 2) + (t % stride);
      const unsigned ixj = i + stride;
      const bool up = ((i & size) == 0);
      unsigned long long a = key[i], c = key[ixj];
      if (up ? (a < c) : (a > c)) { key[i] = c; key[ixj] = a; }
      __syncthreads();
    }
  }
  const unsigned my = ~(unsigned)(key[t] & 0xFFFFFFFFull);
  __syncthreads();
  unsigned* arr = (unsigned*)key;
  arr[t] = my;
  __syncthreads();
  for (unsigned size = 2; size <= (unsigned)k; size <<= 1) {
    for (unsigned stride = size >> 1; stride > 0; stride >>= 1) {
      if (t < (unsigned)k / 2) {
        const unsigned i = (t / stride) * (stride * 2) + (t % stride);
        const unsigned ixj = i + stride;
        const bool up = ((i & size) == 0);
        unsigned a = arr[i], c = arr[ixj];
        if (up ? (a > c) : (a < c)) { arr[i] = c; arr[ixj] = a; }
      }
      __syncthreads();
    }
  }
  idx_out[(size_t)b * k + t] = (int)arr[t];
}

// ---------------------------------------------------------------------------
// gather pooled rows + li/lj attention dots
// ---------------------------------------------------------------------------
__global__ __launch_bounds__(256) void gather_li_kernel(
    const float* __restrict__ X, int src_n,
    const int* __restrict__ idx, int k,
    const float* __restrict__ att,
    float* __restrict__ xk, float* __restrict__ li, float* __restrict__ lj)
{
  __shared__ float redA[256], redB[256];
  const int b = blockIdx.y, r = blockIdx.x, t = threadIdx.x;
  const int g = idx[(size_t)b * k + r];
  const float* src = X + ((size_t)(b * src_n + g)) * 512;
  float* dst = xk + ((size_t)(b * k + r)) * 512;
  const float v0 = src[t], v1 = src[t + 256];
  dst[t] = v0; dst[t + 256] = v1;
  redA[t] = v0 * att[t] + v1 * att[t + 256];
  redB[t] = v0 * att[512 + t] + v1 * att[512 + t + 256];
  __syncthreads();
  for (int off = 128; off > 0; off >>= 1) {
    if (t < off) { redA[t] += redA[t + off]; redB[t] += redB[t + off]; }
    __syncthreads();
  }
  if (t == 0) { li[(size_t)b * k + r] = redA[0]; lj[(size_t)b * k + r] = redB[0]; }
}

// ---------------------------------------------------------------------------
// structure learning softmax + degree outputs
// ---------------------------------------------------------------------------
__global__ __launch_bounds__(256) void slearn_kernel(
    const float* __restrict__ Asrc, int src_n,
    const int* __restrict__ idx, int k,
    const float* __restrict__ li, const float* __restrict__ lj,
    float* __restrict__ adj_out, float* __restrict__ dg, float* __restrict__ dp)
{
  __shared__ int gidx[1024];
  __shared__ float ljv[1024];
  __shared__ float lg[1024];
  __shared__ float red[256];
  const int b = blockIdx.y, r = blockIdx.x, t = threadIdx.x;
  for (int j = t; j < k; j += 256) { gidx[j] = idx[(size_t)b * k + j]; ljv[j] = lj[(size_t)b * k + j]; }
  __syncthreads();
  const int gi = gidx[r];
  const float lir = li[(size_t)b * k + r];
  const float* ar = Asrc + ((size_t)(b * src_n + gi)) * src_n;
  float mx = -3.4e38f;
  for (int j = t; j < k; j += 256) {
    float v = lir + ljv[j] + ar[gidx[j]];
    lg[j] = v; mx = fmaxf(mx, v);
  }
  red[t] = mx; __syncthreads();
  for (int off = 128; off > 0; off >>= 1) {
    if (t < off) red[t] = fmaxf(red[t], red[t + off]);
    __syncthreads();
  }
  const float m = red[0]; __syncthreads();
  float sm = 0.f;
  for (int j = t; j < k; j += 256) { float e = expf(lg[j] - m); lg[j] = e; sm += e; }
  red[t] = sm; __syncthreads();
  for (int off = 128; off > 0; off >>= 1) {
    if (t < off) red[t] += red[t + off];
    __syncthreads();
  }
  const float s = red[0]; __syncthreads();
  const float inv = 1.f / s;
  float ps = 0.f;
  float* orow = adj_out + ((size_t)(b * k + r)) * k;
  for (int j = t; j < k; j += 256) { float p = lg[j] * inv; orow[j] = p; ps += p; }
  red[t] = ps; __syncthreads();
  for (int off = 128; off > 0; off >>= 1) {
    if (t < off) red[t] += red[t + off];
    __syncthreads();
  }
  if (t == 0) {
    float S = red[0];
    dg[(size_t)b * k + r] = rsqrtf(fmaxf(S + 1.f, 1e-12f));
    dp[(size_t)b * k + r] = 1.f / fmaxf(S, 1.f);
  }
}

// ---------------------------------------------------------------------------
// score = rowsum |X - P| (512 cols)
// ---------------------------------------------------------------------------
__global__ __launch_bounds__(512) void absdiff_kernel(
    const float* __restrict__ X, const float* __restrict__ P, float* __restrict__ score)
{
  __shared__ float red[512];
  const int row = blockIdx.x, t = threadIdx.x;
  float d = fabsf(X[(size_t)row * 512 + t] - P[(size_t)row * 512 + t]);
  red[t] = d; __syncthreads();
  for (int off = 256; off > 0; off >>= 1) {
    if (t < off) red[t] += red[t + off];
    __syncthreads();
  }
  if (t == 0) score[row] = red[0];
}

// ---------------------------------------------------------------------------
// readout: out[b, 0:512] = colmax, out[b, 512:1024] = colmean over nrows
// ---------------------------------------------------------------------------
__global__ __launch_bounds__(512) void readout_kernel(
    const float* __restrict__ X, int nrows, float* __restrict__ out)
{
  const int b = blockIdx.x, c = threadIdx.x;
  const float* xb = X + (size_t)b * nrows * 512;
  float mx = -3.4e38f, sm = 0.f;
  for (int r = 0; r < nrows; ++r) {
    float v = xb[(size_t)r * 512 + c];
    mx = fmaxf(mx, v); sm += v;
  }
  out[(size_t)b * 1024 + c] = mx;
  out[(size_t)b * 1024 + 512 + c] = sm / (float)nrows;
}

// ---------------------------------------------------------------------------
// final MLP head + log_softmax
// ---------------------------------------------------------------------------
__global__ __launch_bounds__(512) void final_mlp_kernel(
    const float* __restrict__ r1, const float* __restrict__ r2, const float* __restrict__ r3,
    const float* __restrict__ fc1W, const float* __restrict__ fc1b,
    const float* __restrict__ fc2W, const float* __restrict__ fc2b,
    const float* __restrict__ fc3W, const float* __restrict__ fc3b,
    float* __restrict__ out)
{
  __shared__ float z[1024];
  __shared__ float z1[512];
  __shared__ float z2[256];
  __shared__ float l[2];
  const int b = blockIdx.x, t = threadIdx.x;
  for (int c = t; c < 1024; c += 512)
    z[c] = fmaxf(r1[(size_t)b * 1024 + c], 0.f) + fmaxf(r2[(size_t)b * 1024 + c], 0.f)
         + fmaxf(r3[(size_t)b * 1024 + c], 0.f);
  __syncthreads();
  {
    float acc = fc1b[t];
    for (int i = 0; i < 1024; ++i) acc = fmaf(z[i], fc1W[(size_t)i * 512 + t], acc);
    z1[t] = fmaxf(acc, 0.f);
  }
  __syncthreads();
  if (t < 256) {
    float acc = fc2b[t];
    for (int i = 0; i < 512; ++i) acc = fmaf(z1[i], fc2W[(size_t)i * 256 + t], acc);
    z2[t] = fmaxf(acc, 0.f);
  }
  __syncthreads();
  if (t < 2) {
    float acc = fc3b[t];
    for (int i = 0; i < 256; ++i) acc = fmaf(z2[i], fc3W[(size_t)i * 2 + t], acc);
    l[t] = acc;
  }
  __syncthreads();
  if (t == 0) {
    float m = fmaxf(l[0], l[1]);
    float ls = m + logf(expf(l[0] - m) + expf(l[1] - m));
    out[b * 2 + 0] = l[0] - ls;
    out[b * 2 + 1] = l[1] - ls;
  }
}

// ---------------------------------------------------------------------------
extern "C" void kernel_launch(void* const* d_in, const int* in_sizes, int n_in,
                              void* d_out, int out_size, void* d_ws, size_t ws_size,
                              hipStream_t stream)
{
  (void)in_sizes; (void)n_in; (void)out_size; (void)ws_size;
  const float* x       = (const float*)d_in[0];
  const float* adj     = (const float*)d_in[1];
  const float* lin1_W  = (const float*)d_in[2];
  const float* lin1_b  = (const float*)d_in[3];
  const float* lin2_W  = (const float*)d_in[4];
  const float* lin2_b  = (const float*)d_in[5];
  const float* conv1_W = (const float*)d_in[6];
  const float* conv1_b = (const float*)d_in[7];
  const float* conv2_W = (const float*)d_in[8];
  const float* conv2_b = (const float*)d_in[9];
  const float* conv3_W = (const float*)d_in[10];
  const float* conv3_b = (const float*)d_in[11];
  const float* att1    = (const float*)d_in[12];
  const float* att2    = (const float*)d_in[13];
  const float* fc1_W   = (const float*)d_in[14];
  const float* fc1_b   = (const float*)d_in[15];
  const float* fc2_W   = (const float*)d_in[16];
  const float* fc2_b   = (const float*)d_in[17];
  const float* fc3_W   = (const float*)d_in[18];
  const float* fc3_b   = (const float*)d_in[19];
  float* ws  = (float*)d_ws;
  float* out = (float*)d_out;

  // fp32 workspace regions (liveness-checked aliases)
  float* h     = ws + 0;                       // [4,2048,544]   dead after xw GEMM
  float* adj1  = ws + 0;                       // [4,1024,1024]  alias (step 9+)
  float* xw    = ws + 4456448;                 // [4,2048,512]   dead after conv1 msg
  float* prop2 = xw;                           // [4,1024,512]   (steps 13-14)
  float* xk2   = ws + 4456448 + 2097152;       // [4,512,512]
  float* adj2  = ws + 4456448 + 3145728;       // [4,512,512]
  float* h1    = ws + 8650752;                 // [4,2048,512]   (steps 5-8)
  float* xk1   = ws + 12845056;                // [4,1024,512]   (steps 8-11)
  float* xw3   = xk1;                          // [4,512,512]    alias (19-20)
  float* h3    = ws + 12845056 + 1048576;      // [4,512,512]
  float* xw2   = ws + 14942208;                // [4,1024,512]
  float* h2    = ws + 17039360;                // [4,1024,512]
  float* S     = ws + 19136512;                // small arrays
  float* dinv_g1 = S;
  float* dinv_p1 = S + 8192;
  float* score1  = S + 16384;
  int*   idx1    = (int*)(S + 24576);
  float* li1     = S + 28672;
  float* lj1     = S + 32768;
  float* r1      = S + 36864;
  float* dinv_g2 = S + 40960;
  float* dinv_p2 = S + 45056;
  float* score2  = S + 49152;
  int*   idx2    = (int*)(S + 53248);
  float* li2     = S + 55296;
  float* lj2     = S + 57344;
  float* r2      = S + 59392;
  float* dinv_g3 = S + 63488;
  float* dinv_p3 = S + 65536;
  float* r3      = S + 67584;

  // bf16 pre-split/transposed B operands, placed in dead fp32 regions:
  __bf16* l1TH  = (__bf16*)(ws + 8650752);     // 6144*512 each; dead before h1
  __bf16* l1TL  = l1TH + 6144 * 512;
  __bf16* c1TH  = (__bf16*)(ws + 12845056);    // 512*544; dead before xk1
  __bf16* c1TL  = c1TH + 512 * 544;
  __bf16* c2TH  = (__bf16*)(ws + 17039360);    // 512*512; dead before h2
  __bf16* c2TL  = c2TH + 512 * 512;
  __bf16* c3TH  = (__bf16*)(ws + 4456448);     // 512*512; written after absdiff
  __bf16* c3TL  = c3TH + 512 * 512;
  __bf16* xw2TH = (__bf16*)(ws + 12845056);    // [4][512][1024]; after gemm 11
  __bf16* xw2TL = xw2TH + 4 * 512 * 1024;
  __bf16* h2TH  = (__bf16*)(ws + 8650752);     // [4][512][1024]; after gemm 12
  __bf16* h2TL  = h2TH + 4 * 512 * 1024;
  __bf16* xw3TH = (__bf16*)(ws + 10747904);    // [4][512][512]; after gemm 19
  __bf16* xw3TL = xw3TH + 4 * 512 * 512;

  dim3 tb32(32, 8);

  // 0. weight pre-split/transpose (lin1, conv1, conv2)
  split_transpose_kernel<<<dim3(16, 192, 1), tb32, 0, stream>>>(lin1_W, 0, 6144, 512, l1TH, l1TL, 0, 6144);
  split_transpose_kernel<<<dim3(16, 17, 1), tb32, 0, stream>>>(conv1_W, 0, 533, 512, c1TH, c1TL, 0, 544);
  split_transpose_kernel<<<dim3(16, 16, 1), tb32, 0, stream>>>(conv2_W, 0, 512, 512, c2TH, c2TL, 0, 512);
  // 1. lin2 -> h[:, 0:21]; pad h[:, 533:544) = 0
  lin2_kernel<<<(4 * 2048 * 21 + 255) / 256, 256, 0, stream>>>(x, lin2_W, lin2_b, h);
  pad_h_kernel<<<(4 * 2048 * 11 + 255) / 256, 256, 0, stream>>>(h);
  // 2. lin1 -> h[:, 21:533]
  gemm_mfma<<<dim3(4, 128, 1), 256, 0, stream>>>(x + 21, 6165, 0, l1TH, l1TL, 6144, 0,
      h + 21, 544, 0, 8192, 512, 6144, lin1_b, nullptr, nullptr, 0, 0, 1);
  // 3. degrees of adj
  degrees_kernel<<<8192, 256, 0, stream>>>(adj, dinv_g1, dinv_p1);
  // 4. xw = h @ conv1_W  (K padded to 544)
  gemm_mfma<<<dim3(4, 128, 1), 256, 0, stream>>>(h, 544, 0, c1TH, c1TL, 544, 0,
      xw, 512, 0, 8192, 512, 544, nullptr, nullptr, nullptr, 0, 0, 0);
  // 5. h1 = relu(gcn message passing) (sparse)
  conv1_msg_kernel<<<dim3(2048, 4), 256, 0, stream>>>(adj, xw, dinv_g1, conv1_b, h1);
  // 6. pool1 scores (sparse)
  pool1_score_kernel<<<dim3(2048, 4), 256, 0, stream>>>(adj, h1, dinv_p1, score1);
  // 7. top-k 2048 -> 1024
  topk_kernel<<<4, 1024, 0, stream>>>(score1, idx1, 2048, 1024);
  // 8. gather xk1, li1, lj1
  gather_li_kernel<<<dim3(1024, 4), 256, 0, stream>>>(h1, 2048, idx1, 1024, att1, xk1, li1, lj1);
  // 9. adj1 softmax structure learning; dinv for conv2/pool2
  slearn_kernel<<<dim3(1024, 4), 256, 0, stream>>>(adj, 2048, idx1, 1024, li1, lj1, adj1, dinv_g2, dinv_p2);
  // 10. r1 readout
  readout_kernel<<<4, 512, 0, stream>>>(xk1, 1024, r1);
  // 11. xw2 = dinv_g2 * (xk1 @ conv2_W)
  gemm_mfma<<<dim3(4, 64, 1), 256, 0, stream>>>(xk1, 512, 0, c2TH, c2TL, 512, 0,
      xw2, 512, 0, 4096, 512, 512, nullptr, dinv_g2, nullptr, 0, 0, 0);
  // 11b. split xw2 -> xw2T
  split_transpose_kernel<<<dim3(16, 32, 4), tb32, 0, stream>>>(xw2, 524288, 1024, 512, xw2TH, xw2TL, 524288, 1024);
  // 12. h2 = relu(dinv_g2 * (adj1 @ xw2 + xw2) + b2)
  gemm_mfma<<<dim3(4, 16, 4), 256, 0, stream>>>(adj1, 1024, 1048576, xw2TH, xw2TL, 1024, 524288,
      h2, 512, 524288, 1024, 512, 1024, conv2_b, dinv_g2, xw2, 524288, 512, 1);
  // 12b. split h2 -> h2T
  split_transpose_kernel<<<dim3(16, 32, 4), tb32, 0, stream>>>(h2, 524288, 1024, 512, h2TH, h2TL, 524288, 1024);
  // 13. prop2 = dinv_p2 * (adj1 @ h2)
  gemm_mfma<<<dim3(4, 16, 4), 256, 0, stream>>>(adj1, 1024, 1048576, h2TH, h2TL, 1024, 524288,
      prop2, 512, 524288, 1024, 512, 1024, nullptr, dinv_p2, nullptr, 0, 0, 0);
  // 14. score2
  absdiff_kernel<<<4096, 512, 0, stream>>>(h2, prop2, score2);
  // 14b. split conv3_W (region shared with prop2, now dead)
  split_transpose_kernel<<<dim3(16, 16, 1), tb32, 0, stream>>>(conv3_W, 0, 512, 512, c3TH, c3TL, 0, 512);
  // 15. top-k 1024 -> 512
  topk_kernel<<<4, 512, 0, stream>>>(score2, idx2, 1024, 512);
  // 16. gather xk2, li2, lj2
  gather_li_kernel<<<dim3(512, 4), 256, 0, stream>>>(h2, 1024, idx2, 512, att2, xk2, li2, lj2);
  // 17. adj2 + dinv for conv3
  slearn_kernel<<<dim3(512, 4), 256, 0, stream>>>(adj1, 1024, idx2, 512, li2, lj2, adj2, dinv_g3, dinv_p3);
  // 18. r2 readout
  readout_kernel<<<4, 512, 0, stream>>>(xk2, 512, r2);
  // 19. xw3 = dinv_g3 * (xk2 @ conv3_W)
  gemm_mfma<<<dim3(4, 32, 1), 256, 0, stream>>>(xk2, 512, 0, c3TH, c3TL, 512, 0,
      xw3, 512, 0, 2048, 512, 512, nullptr, dinv_g3, nullptr, 0, 0, 0);
  // 19b. split xw3 -> xw3T
  split_transpose_kernel<<<dim3(16, 16, 4), tb32, 0, stream>>>(xw3, 262144, 512, 512, xw3TH, xw3TL, 262144, 512);
  // 20. h3 = relu(dinv_g3 * (adj2 @ xw3 + xw3) + b3)
  gemm_mfma<<<dim3(4, 8, 4), 256, 0, stream>>>(adj2, 512, 262144, xw3TH, xw3TL, 512, 262144,
      h3, 512, 262144, 512, 512, 512, conv3_b, dinv_g3, xw3, 262144, 512, 1);
  // 21. r3 readout
  readout_kernel<<<4, 512, 0, stream>>>(h3, 512, r3);
  // 22. head
  final_mlp_kernel<<<4, 512, 0, stream>>>(r1, r2, r3, fc1_W, fc1_b, fc2_W, fc2_b,
                                          fc3_W, fc3_b, out);
}